// Round 6
// baseline (741.179 us; speedup 1.0000x reference)
//
#include <hip/hip_runtime.h>
#include <hip/hip_cooperative_groups.h>

namespace cg = cooperative_groups;

#define D 128
#define SCAN_B 256
#define COOP_G 1024

typedef short bf16x8 __attribute__((ext_vector_type(8)));
typedef float f32x4 __attribute__((ext_vector_type(4)));

static __device__ __forceinline__ unsigned short f2bf(float f) {
  union { float f; unsigned u; } v; v.f = f;
  return (unsigned short)((v.u + 0x7FFF + ((v.u >> 16) & 1)) >> 16);   // RNE
}
static __device__ __forceinline__ float bf2f(unsigned short h) {
  union { unsigned u; float f; } v; v.u = ((unsigned)h) << 16;
  return v.f;
}
static __device__ __forceinline__ float bflo(unsigned u) {
  union { unsigned u; float f; } v; v.u = u << 16; return v.f;
}
static __device__ __forceinline__ float bfhi(unsigned u) {
  union { unsigned u; float f; } v; v.u = u & 0xFFFF0000u; return v.f;
}

// ---------------------------------------------------------------------------
// GEMM tile body (R5's proven wave code), shared by coop + fallback kernels.
// 128 nodes per tile, 4 waves, 32 rows/wave, pass-decomposed (matxch).
// ---------------------------------------------------------------------------
static __device__ __forceinline__ void gemm_tile(
    int tileIdx, int tid, const float* __restrict__ x,
    const unsigned short* __restrict__ Wb, const float* __restrict__ bias,
    float* __restrict__ out, unsigned short* __restrict__ xfb, int nN) {
  const int w = tid >> 6, lane = tid & 63;
  const int q = lane >> 4, r = lane & 15;
  const int g0 = tileIdx * 128 + w * 32;

  int row0 = g0 + r;        if (row0 >= nN) row0 = nN - 1;
  int row1 = g0 + 16 + r;   if (row1 >= nN) row1 = nN - 1;
  const float* xr0 = x + (size_t)row0 * D;
  const float* xr1 = x + (size_t)row1 * D;

  bf16x8 a0[4], a1[4];
  #pragma unroll
  for (int kt = 0; kt < 4; ++kt) {
    const float* p0 = xr0 + kt * 32 + q * 8;
    const float* p1 = xr1 + kt * 32 + q * 8;
    const float4 u0 = *(const float4*)p0;
    const float4 u1 = *(const float4*)(p0 + 4);
    const float4 v0 = *(const float4*)p1;
    const float4 v1 = *(const float4*)(p1 + 4);
    a0[kt][0] = (short)f2bf(u0.x); a0[kt][1] = (short)f2bf(u0.y);
    a0[kt][2] = (short)f2bf(u0.z); a0[kt][3] = (short)f2bf(u0.w);
    a0[kt][4] = (short)f2bf(u1.x); a0[kt][5] = (short)f2bf(u1.y);
    a0[kt][6] = (short)f2bf(u1.z); a0[kt][7] = (short)f2bf(u1.w);
    a1[kt][0] = (short)f2bf(v0.x); a1[kt][1] = (short)f2bf(v0.y);
    a1[kt][2] = (short)f2bf(v0.z); a1[kt][3] = (short)f2bf(v0.w);
    a1[kt][4] = (short)f2bf(v1.x); a1[kt][5] = (short)f2bf(v1.y);
    a1[kt][6] = (short)f2bf(v1.z); a1[kt][7] = (short)f2bf(v1.w);
  }

  #pragma unroll
  for (int mat = 0; mat < 2; ++mat) {
    #pragma unroll
    for (int ch = 0; ch < 2; ++ch) {
      f32x4 acc0[4], acc1[4];
      #pragma unroll
      for (int c2 = 0; c2 < 4; ++c2) { acc0[c2] = (f32x4)0.f; acc1[c2] = (f32x4)0.f; }

      #pragma unroll
      for (int kt = 0; kt < 4; ++kt) {
        #pragma unroll
        for (int c2 = 0; c2 < 4; ++c2) {
          const int ct = ch * 4 + c2;
          const bf16x8 bfr = *(const bf16x8*)(Wb + ((mat * 8 + ct) * 4 + kt) * 512 + lane * 8);
          acc0[c2] = __builtin_amdgcn_mfma_f32_16x16x32_bf16(a0[kt], bfr, acc0[c2], 0, 0, 0);
          acc1[c2] = __builtin_amdgcn_mfma_f32_16x16x32_bf16(a1[kt], bfr, acc1[c2], 0, 0, 0);
        }
      }

      #pragma unroll
      for (int c2 = 0; c2 < 4; ++c2) {
        const int col = (ch * 4 + c2) * 16 + r;
        if (mat == 0) {
          const float bv = bias[col];
          #pragma unroll
          for (int reg = 0; reg < 4; ++reg) {
            const int ra = g0 + q * 4 + reg;
            const int rb = g0 + 16 + q * 4 + reg;
            if (ra < nN) out[(size_t)ra * D + col] = acc0[c2][reg] + bv;
            if (rb < nN) out[(size_t)rb * D + col] = acc1[c2][reg] + bv;
          }
        } else {
          #pragma unroll
          for (int reg = 0; reg < 4; ++reg) {
            const int ra = g0 + q * 4 + reg;
            const int rb = g0 + 16 + q * 4 + reg;
            if (ra < nN) xfb[(size_t)ra * D + col] = f2bf(acc0[c2][reg]);
            if (rb < nN) xfb[(size_t)rb * D + col] = f2bf(acc1[c2][reg]);
          }
        }
      }
    }
  }
}

// ---------------------------------------------------------------------------
// prep_kernel (fused): blocks [0,16)   : Wself/Wfwd -> bf16 MFMA-B-swizzled Wb
//                      blocks [16,+rB) : rel path (2 rel rows per block)
//                      rest            : zero offs (int4 stores)
// ---------------------------------------------------------------------------
__global__ __launch_bounds__(256) void prep_kernel(
    const float* __restrict__ Wself, const float* __restrict__ Wfwd,
    const float* __restrict__ rel, const float* __restrict__ Wr,
    unsigned short* __restrict__ Wb, unsigned short* __restrict__ rfb,
    float* __restrict__ rel_out, int* __restrict__ offs,
    int nR, int nN, int relBlocks) {
  const int tid = threadIdx.x;
  if ((int)blockIdx.x < 16) {
    const int g = blockIdx.x * 256 + tid;     // 0..4095
    const int frag = g >> 6, lane = g & 63;
    const int mat = frag >> 5, ct = (frag >> 2) & 7, kt = frag & 3;
    const int q = lane >> 4, r = lane & 15;
    const float* W = mat ? Wfwd : Wself;
    const float* src = W + (ct * 16 + r) * D + kt * 32 + q * 8;
    unsigned short* dst = Wb + frag * 512 + lane * 8;
    #pragma unroll
    for (int j = 0; j < 8; ++j) dst[j] = f2bf(src[j]);
  } else if ((int)blockIdx.x < 16 + relBlocks) {
    __shared__ float row[2][D];
    const int half = tid >> 7;
    const int c = tid & 127;
    const int rr = ((int)blockIdx.x - 16) * 2 + half;
    const int r2 = (rr < nR) ? rr : nR - 1;
    row[half][c] = rel[r2 * D + c];
    __syncthreads();
    float af = 0.f, ar = 0.f;
    #pragma unroll 8
    for (int k = 0; k < D; ++k) {
      const float xv = row[half][k];
      af += xv * Wfwd[c * D + k];
      ar += xv * Wr[c * D + k];
    }
    if (rr < nR) {
      rfb[rr * D + c] = f2bf(af);
      rel_out[rr * D + c] = ar;
    }
  } else {
    const int i = ((int)blockIdx.x - 16 - relBlocks) * 256 + tid;
    const int e0 = i * 4;
    if (e0 < nN) {
      if (e0 + 3 < nN) ((int4*)offs)[i] = make_int4(0, 0, 0, 0);
      else { for (int k = e0; k < nN; ++k) offs[k] = 0; }
    }
  }
}

// ---------------------------------------------------------------------------
// coop_main (ONE cooperative dispatch):
//   Phase A : blocks [0,gemmBlocks) GEMM tiles || rest: dst histogram
//   Phase B1: per-chunk (512 elems) partial sums -> bsum
//   Phase B2: block 0 exclusive-scans bsum (nChunks <= 256)
//   Phase B3: per-chunk exclusive scan + chunk base -> offs (exclusive starts)
//   Phase C : fill packed meta via atomic cursors (offs becomes bucket ends)
// csr_agg stays a separate dispatch (wants >4 blocks/CU occupancy).
// ---------------------------------------------------------------------------
__global__ __launch_bounds__(256, 4) void coop_main(
    const float* __restrict__ x, const unsigned short* __restrict__ Wb,
    const float* __restrict__ bias, const int* __restrict__ src,
    const int* __restrict__ dstv, const int* __restrict__ et,
    const float* __restrict__ ew, float* __restrict__ out,
    unsigned short* __restrict__ xfb, int* __restrict__ offs,
    int* __restrict__ bsum, uint2* __restrict__ meta,
    int nN, int nE, int gemmBlocks, int nChunks) {
  cg::grid_group grid = cg::this_grid();
  __shared__ int sd[256];
  const int b = blockIdx.x;
  const int tid = threadIdx.x;
  const int G = (int)gridDim.x;

  // ---- Phase A: GEMM || histogram ----
  if (b < gemmBlocks) {
    gemm_tile(b, tid, x, Wb, bias, out, xfb, nN);
  } else {
    const int S = G - gemmBlocks;
    const int sb = b - gemmBlocks;
    const int nQ = nE >> 2;
    for (int i = sb * 256 + tid; i < nQ; i += S * 256) {
      const int4 d4 = ((const int4*)dstv)[i];
      atomicAdd(&offs[d4.x], 1); atomicAdd(&offs[d4.y], 1);
      atomicAdd(&offs[d4.z], 1); atomicAdd(&offs[d4.w], 1);
    }
    for (int e = (nQ << 2) + sb * 256 + tid; e < nE; e += S * 256)
      atomicAdd(&offs[dstv[e]], 1);
  }
  grid.sync();

  // ---- Phase B1: chunk partial sums ----
  for (int c = b; c < nChunks; c += G) {
    const int2 v = ((const int2*)offs)[c * 256 + tid];
    sd[tid] = v.x + v.y;
    __syncthreads();
    for (int s = 128; s > 0; s >>= 1) {
      if (tid < s) sd[tid] += sd[tid + s];
      __syncthreads();
    }
    if (tid == 0) bsum[c] = sd[0];
    __syncthreads();
  }
  grid.sync();

  // ---- Phase B2: exclusive scan of bsum (single block) ----
  if (b == 0) {
    const int v = (tid < nChunks) ? bsum[tid] : 0;
    sd[tid] = v;
    __syncthreads();
    for (int o = 1; o < 256; o <<= 1) {
      const int add = (tid >= o) ? sd[tid - o] : 0;
      __syncthreads();
      sd[tid] += add;
      __syncthreads();
    }
    if (tid < nChunks) bsum[tid] = sd[tid] - v;   // exclusive
  }
  grid.sync();

  // ---- Phase B3: in-chunk exclusive scan + chunk base ----
  for (int c = b; c < nChunks; c += G) {
    const int2 v = ((const int2*)offs)[c * 256 + tid];
    const int ps = v.x + v.y;
    sd[tid] = ps;
    __syncthreads();
    for (int o = 1; o < 256; o <<= 1) {
      const int add = (tid >= o) ? sd[tid - o] : 0;
      __syncthreads();
      sd[tid] += add;
      __syncthreads();
    }
    const int base = bsum[c] + sd[tid] - ps;      // exclusive start of pair
    ((int2*)offs)[c * 256 + tid] = make_int2(base, base + v.x);
    __syncthreads();
  }
  grid.sync();

  // ---- Phase C: fill packed meta ----
  for (int e = b * 256 + tid; e < nE; e += G * 256) {
    const int p = atomicAdd(&offs[dstv[e]], 1);
    meta[p] = make_uint2((unsigned)src[e] | ((unsigned)et[e] << 20),
                         __float_as_uint(ew[e]));
  }
}

// ---------------------------------------------------------------------------
// csr_agg: out[n,:] += sum_{e in bucket(n)} ew*(xfb[src]-rfb[et]).
// 16 lanes/node, uint4 (16B) bf16 gathers, shuffle-broadcast packed meta.
// ---------------------------------------------------------------------------
__global__ __launch_bounds__(256) void csr_agg(
    const uint4* __restrict__ xfb4, const uint4* __restrict__ rfb4,
    const uint2* __restrict__ meta, const int* __restrict__ offs,
    float* __restrict__ out, int nN) {
  const int n = blockIdx.x * 16 + ((int)threadIdx.x >> 4);
  if (n >= nN) return;
  const int lane = threadIdx.x & 15;
  const int end = offs[n];
  const int start = (n == 0) ? 0 : offs[n - 1];

  float acc[8] = {0.f, 0.f, 0.f, 0.f, 0.f, 0.f, 0.f, 0.f};
  for (int base = start; base < end; base += 16) {
    int m = end - base; if (m > 16) m = 16;
    uint2 mv = make_uint2(0u, 0u);
    if (lane < m) mv = meta[base + lane];
    for (int j = 0; j < m; ++j) {
      const unsigned pk = (unsigned)__shfl((int)mv.x, j, 16);
      const float wgt = __uint_as_float(__shfl((int)mv.y, j, 16));
      const int s = (int)(pk & 0xFFFFFu);
      const int t = (int)(pk >> 20);
      const uint4 a = xfb4[(size_t)s * 16 + lane];
      const uint4 bb = rfb4[(size_t)t * 16 + lane];
      acc[0] += wgt * (bflo(a.x) - bflo(bb.x));
      acc[1] += wgt * (bfhi(a.x) - bfhi(bb.x));
      acc[2] += wgt * (bflo(a.y) - bflo(bb.y));
      acc[3] += wgt * (bfhi(a.y) - bfhi(bb.y));
      acc[4] += wgt * (bflo(a.z) - bflo(bb.z));
      acc[5] += wgt * (bfhi(a.z) - bfhi(bb.z));
      acc[6] += wgt * (bflo(a.w) - bflo(bb.w));
      acc[7] += wgt * (bfhi(a.w) - bfhi(bb.w));
    }
  }
  float* o = out + (size_t)n * D + lane * 8;
  float4 o0 = *(const float4*)o;
  float4 o1 = *(const float4*)(o + 4);
  o0.x += acc[0]; o0.y += acc[1]; o0.z += acc[2]; o0.w += acc[3];
  o1.x += acc[4]; o1.y += acc[5]; o1.z += acc[6]; o1.w += acc[7];
  *(float4*)o = o0;
  *(float4*)(o + 4) = o1;
}

// ===========================================================================
// Fallback path (R5 structure) if cooperative launch unavailable
// ===========================================================================
__global__ __launch_bounds__(256, 4) void fused_main(
    const float* __restrict__ x, const unsigned short* __restrict__ Wb,
    const float* __restrict__ bias, const int* __restrict__ dst,
    float* __restrict__ out, unsigned short* __restrict__ xfb,
    int* __restrict__ offs, int nN, int nE, int gemmBlocks) {
  if ((int)blockIdx.x < gemmBlocks) {
    gemm_tile(blockIdx.x, threadIdx.x, x, Wb, bias, out, xfb, nN);
  } else {
    const int i0 = (((int)blockIdx.x - gemmBlocks) * 256 + (int)threadIdx.x) * 4;
    if (((nE & 3) == 0) && i0 + 3 < nE) {
      const int4 d4 = *(const int4*)(dst + i0);
      atomicAdd(&offs[d4.x], 1); atomicAdd(&offs[d4.y], 1);
      atomicAdd(&offs[d4.z], 1); atomicAdd(&offs[d4.w], 1);
    } else {
      for (int e = i0; e < nE && e < i0 + 4; ++e) atomicAdd(&offs[dst[e]], 1);
    }
  }
}

__global__ __launch_bounds__(SCAN_B) void scan_pass1(
    const int* __restrict__ deg, int* __restrict__ bsum, int n) {
  __shared__ int sd[SCAN_B];
  const int i = blockIdx.x * SCAN_B + threadIdx.x;
  sd[threadIdx.x] = (i < n) ? deg[i] : 0;
  __syncthreads();
  for (int s = SCAN_B / 2; s > 0; s >>= 1) {
    if (threadIdx.x < s) sd[threadIdx.x] += sd[threadIdx.x + s];
    __syncthreads();
  }
  if (threadIdx.x == 0) bsum[blockIdx.x] = sd[0];
}

__global__ __launch_bounds__(1024) void scan_pass2(int* __restrict__ bsum, int nb) {
  __shared__ int sd[1024];
  const int t = threadIdx.x;
  const int v = (t < nb) ? bsum[t] : 0;
  sd[t] = v;
  __syncthreads();
  for (int off = 1; off < 1024; off <<= 1) {
    const int add = (t >= off) ? sd[t - off] : 0;
    __syncthreads();
    sd[t] += add;
    __syncthreads();
  }
  if (t < nb) bsum[t] = sd[t] - v;
}

__global__ __launch_bounds__(SCAN_B) void scan_pass3(
    int* __restrict__ deg_offs, const int* __restrict__ bsum, int n) {
  __shared__ int sd[SCAN_B];
  const int i = blockIdx.x * SCAN_B + threadIdx.x;
  const int t = threadIdx.x;
  const int v = (i < n) ? deg_offs[i] : 0;
  sd[t] = v;
  __syncthreads();
  for (int off = 1; off < SCAN_B; off <<= 1) {
    const int add = (t >= off) ? sd[t - off] : 0;
    __syncthreads();
    sd[t] += add;
    __syncthreads();
  }
  if (i < n) deg_offs[i] = sd[t] - v + bsum[blockIdx.x];
}

__global__ void fill_kernel(const int* __restrict__ src, const int* __restrict__ dstv,
                            const int* __restrict__ et, const float* __restrict__ ew,
                            int* __restrict__ cursor, uint2* __restrict__ meta, int nE) {
  const int e = blockIdx.x * blockDim.x + threadIdx.x;
  if (e < nE) {
    const int p = atomicAdd(&cursor[dstv[e]], 1);
    meta[p] = make_uint2((unsigned)src[e] | ((unsigned)et[e] << 20),
                         __float_as_uint(ew[e]));
  }
}

__global__ __launch_bounds__(256) void edge_scatter(
    const unsigned short* __restrict__ xfb, const unsigned short* __restrict__ rfb,
    const int* __restrict__ ei, const int* __restrict__ etype,
    const float* __restrict__ ew, float* __restrict__ out, int nE) {
  const int e = blockIdx.x * 8 + ((int)threadIdx.x >> 5);
  if (e >= nE) return;
  const int lane = threadIdx.x & 31;
  const int s = ei[e];
  const int d = ei[nE + e];
  const int t = etype[e];
  const float w = ew[e];
  const ushort4 a = ((const ushort4*)(xfb + (size_t)s * D))[lane];
  const ushort4 b = ((const ushort4*)(rfb + (size_t)t * D))[lane];
  float* o = out + (size_t)d * D + lane * 4;
  atomicAdd(o + 0, w * (bf2f(a.x) - bf2f(b.x)));
  atomicAdd(o + 1, w * (bf2f(a.y) - bf2f(b.y)));
  atomicAdd(o + 2, w * (bf2f(a.z) - bf2f(b.z)));
  atomicAdd(o + 3, w * (bf2f(a.w) - bf2f(b.w)));
}

// ---------------------------------------------------------------------------
extern "C" void kernel_launch(void* const* d_in, const int* in_sizes, int n_in,
                              void* d_out, int out_size, void* d_ws, size_t ws_size,
                              hipStream_t stream) {
  const float* x      = (const float*)d_in[0];
  const int*   ei     = (const int*)d_in[1];
  const int*   etype  = (const int*)d_in[2];
  const float* rel    = (const float*)d_in[3];
  const float* ew     = (const float*)d_in[4];
  const float* Wself  = (const float*)d_in[5];
  const float* Wfwd   = (const float*)d_in[6];
  const float* Wrel   = (const float*)d_in[7];
  const float* bias   = (const float*)d_in[8];

  const int nN = in_sizes[0] / D;       // 100000
  const int nE = in_sizes[2];           // 625000
  const int nR = in_sizes[3] / D;       // 200

  float* out     = (float*)d_out;
  float* rel_out = (float*)d_out + (size_t)nN * D;

  const int nChunks = (nN + 511) / 512;           // 512-elem scan chunks

  // workspace carve-up (256B-aligned)
  char* w = (char*)d_ws;
  size_t off = 0;
  auto carve = [&](size_t bytes) {
    char* p = w + off;
    off = (off + bytes + 255) & ~(size_t)255;
    return p;
  };
  unsigned short* xfb = (unsigned short*)carve((size_t)nN * D * sizeof(unsigned short));
  unsigned short* rfb = (unsigned short*)carve((size_t)nR * D * sizeof(unsigned short));
  unsigned short* Wb  = (unsigned short*)carve(2 * 8 * 4 * 512 * sizeof(unsigned short));
  int*   offs = (int*)carve((size_t)nChunks * 512 * sizeof(int));  // padded for int2 scan
  uint2* meta = (uint2*)carve((size_t)nE * sizeof(uint2));
  int*   bsum = (int*)carve(1024 * sizeof(int));
  const size_t need = off;

  const int* src = ei;
  const int* dst = ei + nE;
  const int nb = (nN + SCAN_B - 1) / SCAN_B;
  const int relBlocks  = (nR + 1) / 2;
  const int zeroBlocks = (nN + 1023) / 1024;
  const int gemmBlocks = (nN + 127) / 128;
  const int histBlocks = (nE + 1023) / 1024;

  const bool csr_ok = (need <= ws_size) && (nb <= 1024) &&
                      (nN < (1 << 20)) && (nR <= 4096);
  const bool coop_ok = csr_ok && (nChunks <= 256) && (gemmBlocks <= COOP_G - 64);

  // Wb prep + rel path + zero offs (one dispatch)
  prep_kernel<<<16 + relBlocks + zeroBlocks, 256, 0, stream>>>(
      Wself, Wfwd, rel, Wrel, Wb, rfb, rel_out, offs, nR, nN, relBlocks);

  bool coop_done = false;
  if (coop_ok) {
    int nN_a = nN, nE_a = nE, gB_a = gemmBlocks, nC_a = nChunks;
    void* args[] = { (void*)&x, (void*)&Wb, (void*)&bias, (void*)&src,
                     (void*)&dst, (void*)&etype, (void*)&ew, (void*)&out,
                     (void*)&xfb, (void*)&offs, (void*)&bsum, (void*)&meta,
                     (void*)&nN_a, (void*)&nE_a, (void*)&gB_a, (void*)&nC_a };
    hipError_t err = hipLaunchCooperativeKernel(
        (const void*)coop_main, dim3(COOP_G), dim3(256), args, 0, stream);
    coop_done = (err == hipSuccess);
  }

  if (coop_done) {
    csr_agg<<<(nN + 15) / 16, 256, 0, stream>>>(
        (const uint4*)xfb, (const uint4*)rfb, meta, offs, out, nN);
  } else {
    // fallback: R5 multi-dispatch path
    fused_main<<<gemmBlocks + (csr_ok ? histBlocks : 0), 256, 0, stream>>>(
        x, Wb, bias, dst, out, xfb, offs, nN, nE, gemmBlocks);
    if (csr_ok) {
      scan_pass1<<<nb, SCAN_B, 0, stream>>>(offs, bsum, nN);
      scan_pass2<<<1, 1024, 0, stream>>>(bsum, nb);
      scan_pass3<<<nb, SCAN_B, 0, stream>>>(offs, bsum, nN);
      fill_kernel<<<(nE + 255) / 256, 256, 0, stream>>>(ei, dst, etype, ew, offs, meta, nE);
      csr_agg<<<(nN + 15) / 16, 256, 0, stream>>>(
          (const uint4*)xfb, (const uint4*)rfb, meta, offs, out, nN);
    } else {
      edge_scatter<<<(nE + 7) / 8, 256, 0, stream>>>(xfb, rfb, ei, etype, ew, out, nE);
    }
  }
}

// Round 7
// 285.606 us; speedup vs baseline: 2.5951x; 2.5951x over previous
//
#include <hip/hip_runtime.h>

#define D 128

typedef short bf16x8 __attribute__((ext_vector_type(8)));
typedef float f32x4 __attribute__((ext_vector_type(4)));

static __device__ __forceinline__ unsigned short f2bf(float f) {
  union { float f; unsigned u; } v; v.f = f;
  return (unsigned short)((v.u + 0x7FFF + ((v.u >> 16) & 1)) >> 16);   // RNE
}
static __device__ __forceinline__ float bf2f(unsigned short h) {
  union { unsigned u; float f; } v; v.u = ((unsigned)h) << 16;
  return v.f;
}
static __device__ __forceinline__ float bflo(unsigned u) {
  union { unsigned u; float f; } v; v.u = u << 16; return v.f;
}
static __device__ __forceinline__ float bfhi(unsigned u) {
  union { unsigned u; float f; } v; v.u = u & 0xFFFF0000u; return v.f;
}

// ---------------------------------------------------------------------------
// GEMM tile body (R5's proven wave code). 128 nodes/tile, 4 waves, 32 rows
// per wave (two 16-row groups = 2 A-streams), pass-decomposed (mat x ch).
// C/D layout: col=lane&15, row=(lane>>4)*4+reg.
// ---------------------------------------------------------------------------
static __device__ __forceinline__ void gemm_tile(
    int tileIdx, int tid, const float* __restrict__ x,
    const unsigned short* __restrict__ Wb, const float* __restrict__ bias,
    float* __restrict__ out, unsigned short* __restrict__ xfb, int nN) {
  const int w = tid >> 6, lane = tid & 63;
  const int q = lane >> 4, r = lane & 15;
  const int g0 = tileIdx * 128 + w * 32;

  int row0 = g0 + r;        if (row0 >= nN) row0 = nN - 1;
  int row1 = g0 + 16 + r;   if (row1 >= nN) row1 = nN - 1;
  const float* xr0 = x + (size_t)row0 * D;
  const float* xr1 = x + (size_t)row1 * D;

  bf16x8 a0[4], a1[4];
  #pragma unroll
  for (int kt = 0; kt < 4; ++kt) {
    const float* p0 = xr0 + kt * 32 + q * 8;
    const float* p1 = xr1 + kt * 32 + q * 8;
    const float4 u0 = *(const float4*)p0;
    const float4 u1 = *(const float4*)(p0 + 4);
    const float4 v0 = *(const float4*)p1;
    const float4 v1 = *(const float4*)(p1 + 4);
    a0[kt][0] = (short)f2bf(u0.x); a0[kt][1] = (short)f2bf(u0.y);
    a0[kt][2] = (short)f2bf(u0.z); a0[kt][3] = (short)f2bf(u0.w);
    a0[kt][4] = (short)f2bf(u1.x); a0[kt][5] = (short)f2bf(u1.y);
    a0[kt][6] = (short)f2bf(u1.z); a0[kt][7] = (short)f2bf(u1.w);
    a1[kt][0] = (short)f2bf(v0.x); a1[kt][1] = (short)f2bf(v0.y);
    a1[kt][2] = (short)f2bf(v0.z); a1[kt][3] = (short)f2bf(v0.w);
    a1[kt][4] = (short)f2bf(v1.x); a1[kt][5] = (short)f2bf(v1.y);
    a1[kt][6] = (short)f2bf(v1.z); a1[kt][7] = (short)f2bf(v1.w);
  }

  #pragma unroll
  for (int mat = 0; mat < 2; ++mat) {
    #pragma unroll
    for (int ch = 0; ch < 2; ++ch) {
      f32x4 acc0[4], acc1[4];
      #pragma unroll
      for (int c2 = 0; c2 < 4; ++c2) { acc0[c2] = (f32x4)0.f; acc1[c2] = (f32x4)0.f; }

      #pragma unroll
      for (int kt = 0; kt < 4; ++kt) {
        #pragma unroll
        for (int c2 = 0; c2 < 4; ++c2) {
          const int ct = ch * 4 + c2;
          const bf16x8 bfr = *(const bf16x8*)(Wb + ((mat * 8 + ct) * 4 + kt) * 512 + lane * 8);
          acc0[c2] = __builtin_amdgcn_mfma_f32_16x16x32_bf16(a0[kt], bfr, acc0[c2], 0, 0, 0);
          acc1[c2] = __builtin_amdgcn_mfma_f32_16x16x32_bf16(a1[kt], bfr, acc1[c2], 0, 0, 0);
        }
      }

      #pragma unroll
      for (int c2 = 0; c2 < 4; ++c2) {
        const int col = (ch * 4 + c2) * 16 + r;
        if (mat == 0) {
          const float bv = bias[col];
          #pragma unroll
          for (int reg = 0; reg < 4; ++reg) {
            const int ra = g0 + q * 4 + reg;
            const int rb = g0 + 16 + q * 4 + reg;
            if (ra < nN) out[(size_t)ra * D + col] = acc0[c2][reg] + bv;
            if (rb < nN) out[(size_t)rb * D + col] = acc1[c2][reg] + bv;
          }
        } else {
          #pragma unroll
          for (int reg = 0; reg < 4; ++reg) {
            const int ra = g0 + q * 4 + reg;
            const int rb = g0 + 16 + q * 4 + reg;
            if (ra < nN) xfb[(size_t)ra * D + col] = f2bf(acc0[c2][reg]);
            if (rb < nN) xfb[(size_t)rb * D + col] = f2bf(acc1[c2][reg]);
          }
        }
      }
    }
  }
}

// ---------------------------------------------------------------------------
// prep_hist: blocks [0,16)            : Wself/Wfwd -> bf16 B-swizzled Wb
//            blocks [16,16+relBlocks) : rel path (2 rows/block)
//            rest                     : dst histogram into offs (pre-zeroed
//                                       by hipMemsetAsync), grid-strided.
// ---------------------------------------------------------------------------
__global__ __launch_bounds__(256) void prep_hist(
    const float* __restrict__ Wself, const float* __restrict__ Wfwd,
    const float* __restrict__ rel, const float* __restrict__ Wr,
    const int* __restrict__ dstv,
    unsigned short* __restrict__ Wb, unsigned short* __restrict__ rfb,
    float* __restrict__ rel_out, int* __restrict__ offs,
    int nR, int nE, int relBlocks, int histBlocks) {
  const int tid = threadIdx.x;
  if ((int)blockIdx.x < 16) {
    const int g = blockIdx.x * 256 + tid;     // 0..4095
    const int frag = g >> 6, lane = g & 63;
    const int mat = frag >> 5, ct = (frag >> 2) & 7, kt = frag & 3;
    const int q = lane >> 4, r = lane & 15;
    const float* W = mat ? Wfwd : Wself;
    const float* src = W + (ct * 16 + r) * D + kt * 32 + q * 8;
    unsigned short* dst = Wb + frag * 512 + lane * 8;
    #pragma unroll
    for (int j = 0; j < 8; ++j) dst[j] = f2bf(src[j]);
  } else if ((int)blockIdx.x < 16 + relBlocks) {
    __shared__ float row[2][D];
    const int half = tid >> 7;
    const int c = tid & 127;
    const int rr = ((int)blockIdx.x - 16) * 2 + half;
    const int r2 = (rr < nR) ? rr : nR - 1;
    row[half][c] = rel[r2 * D + c];
    __syncthreads();
    float af = 0.f, ar = 0.f;
    #pragma unroll 8
    for (int k = 0; k < D; ++k) {
      const float xv = row[half][k];
      af += xv * Wfwd[c * D + k];
      ar += xv * Wr[c * D + k];
    }
    if (rr < nR) {
      rfb[rr * D + c] = f2bf(af);
      rel_out[rr * D + c] = ar;
    }
  } else {
    const int sb = (int)blockIdx.x - 16 - relBlocks;
    const int S = histBlocks * 256;
    const int nQ = nE >> 2;
    for (int i = sb * 256 + tid; i < nQ; i += S) {
      const int4 d4 = ((const int4*)dstv)[i];
      atomicAdd(&offs[d4.x], 1); atomicAdd(&offs[d4.y], 1);
      atomicAdd(&offs[d4.z], 1); atomicAdd(&offs[d4.w], 1);
    }
    for (int e = (nQ << 2) + sb * 256 + tid; e < nE; e += S)
      atomicAdd(&offs[dstv[e]], 1);
  }
}

// ---------------------------------------------------------------------------
// scan_lookback: single-dispatch exclusive scan (decoupled lookback).
// Chunk = 512 ints (int2/thread). Dynamic block index via atomic ticket
// (flags[0]) guarantees lower chunks are scheduled first -> deadlock-free.
// Status word per chunk: (state<<30)|value; state 1=aggregate, 2=prefix.
// In-place: offs[deg] -> offs[exclusive start].
// ---------------------------------------------------------------------------
__global__ __launch_bounds__(256) void scan_lookback(
    int* __restrict__ offs, unsigned* __restrict__ flags, int nChunks) {
  __shared__ int sd[256];
  __shared__ int sbid, sbase;
  const int tid = threadIdx.x;
  if (tid == 0) sbid = atomicAdd((int*)flags, 1);
  __syncthreads();
  const int c = sbid;
  if (c >= nChunks) return;
  unsigned* st = flags + 2;

  const int2 v = ((const int2*)offs)[c * 256 + tid];
  const int ps = v.x + v.y;
  sd[tid] = ps;
  __syncthreads();
  for (int o = 1; o < 256; o <<= 1) {
    const int add = (tid >= o) ? sd[tid - o] : 0;
    __syncthreads();
    sd[tid] += add;
    __syncthreads();
  }
  const int aggregate = sd[255];

  if (tid == 0) {
    if (c == 0) {
      __hip_atomic_store(&st[0], (2u << 30) | (unsigned)aggregate,
                         __ATOMIC_RELEASE, __HIP_MEMORY_SCOPE_AGENT);
      sbase = 0;
    } else {
      __hip_atomic_store(&st[c], (1u << 30) | (unsigned)aggregate,
                         __ATOMIC_RELEASE, __HIP_MEMORY_SCOPE_AGENT);
      int base = 0;
      for (int j = c - 1; j >= 0;) {
        unsigned wd;
        do {
          wd = __hip_atomic_load(&st[j], __ATOMIC_ACQUIRE, __HIP_MEMORY_SCOPE_AGENT);
        } while ((wd >> 30) == 0u);
        base += (int)(wd & 0x3FFFFFFFu);
        if ((wd >> 30) == 2u) break;
        --j;
      }
      __hip_atomic_store(&st[c], (2u << 30) | (unsigned)(base + aggregate),
                         __ATOMIC_RELEASE, __HIP_MEMORY_SCOPE_AGENT);
      sbase = base;
    }
  }
  __syncthreads();
  const int start = sbase + sd[tid] - ps;        // exclusive start of pair
  ((int2*)offs)[c * 256 + tid] = make_int2(start, start + v.x);
}

// ---------------------------------------------------------------------------
// gemm_fill: blocks [0,gemmBlocks): GEMM tiles.
//            rest: fill packed meta (atomic cursor on offs; starts -> ends).
// fill only depends on the scan; GEMM only on Wb — they co-schedule.
// ---------------------------------------------------------------------------
__global__ __launch_bounds__(256, 4) void gemm_fill(
    const float* __restrict__ x, const unsigned short* __restrict__ Wb,
    const float* __restrict__ bias, const int* __restrict__ src,
    const int* __restrict__ dstv, const int* __restrict__ et,
    const float* __restrict__ ew, float* __restrict__ out,
    unsigned short* __restrict__ xfb, int* __restrict__ offs,
    uint2* __restrict__ meta, int nN, int nE, int gemmBlocks, int fillBlocks) {
  if ((int)blockIdx.x < gemmBlocks) {
    gemm_tile(blockIdx.x, threadIdx.x, x, Wb, bias, out, xfb, nN);
  } else {
    const int sb = (int)blockIdx.x - gemmBlocks;
    const int S = fillBlocks * 256;
    for (int e = sb * 256 + (int)threadIdx.x; e < nE; e += S) {
      const int p = atomicAdd(&offs[dstv[e]], 1);
      meta[p] = make_uint2((unsigned)src[e] | ((unsigned)et[e] << 20),
                           __float_as_uint(ew[e]));
    }
  }
}

// ---------------------------------------------------------------------------
// csr_agg: out[n,:] += sum_{e in bucket(n)} ew*(xfb[src]-rfb[et]).
// 16 lanes/node, uint4 (16B) bf16 gathers, shuffle-broadcast packed meta.
// ---------------------------------------------------------------------------
__global__ __launch_bounds__(256) void csr_agg(
    const uint4* __restrict__ xfb4, const uint4* __restrict__ rfb4,
    const uint2* __restrict__ meta, const int* __restrict__ offs,
    float* __restrict__ out, int nN) {
  const int n = blockIdx.x * 16 + ((int)threadIdx.x >> 4);
  if (n >= nN) return;
  const int lane = threadIdx.x & 15;
  const int end = offs[n];
  const int start = (n == 0) ? 0 : offs[n - 1];

  float acc[8] = {0.f, 0.f, 0.f, 0.f, 0.f, 0.f, 0.f, 0.f};
  for (int base = start; base < end; base += 16) {
    int m = end - base; if (m > 16) m = 16;
    uint2 mv = make_uint2(0u, 0u);
    if (lane < m) mv = meta[base + lane];
    for (int j = 0; j < m; ++j) {
      const unsigned pk = (unsigned)__shfl((int)mv.x, j, 16);
      const float wgt = __uint_as_float(__shfl((int)mv.y, j, 16));
      const int s = (int)(pk & 0xFFFFFu);
      const int t = (int)(pk >> 20);
      const uint4 a = xfb4[(size_t)s * 16 + lane];
      const uint4 bb = rfb4[(size_t)t * 16 + lane];
      acc[0] += wgt * (bflo(a.x) - bflo(bb.x));
      acc[1] += wgt * (bfhi(a.x) - bfhi(bb.x));
      acc[2] += wgt * (bflo(a.y) - bflo(bb.y));
      acc[3] += wgt * (bfhi(a.y) - bfhi(bb.y));
      acc[4] += wgt * (bflo(a.z) - bflo(bb.z));
      acc[5] += wgt * (bfhi(a.z) - bfhi(bb.z));
      acc[6] += wgt * (bflo(a.w) - bflo(bb.w));
      acc[7] += wgt * (bfhi(a.w) - bfhi(bb.w));
    }
  }
  float* o = out + (size_t)n * D + lane * 8;
  float4 o0 = *(const float4*)o;
  float4 o1 = *(const float4*)(o + 4);
  o0.x += acc[0]; o0.y += acc[1]; o0.z += acc[2]; o0.w += acc[3];
  o1.x += acc[4]; o1.y += acc[5]; o1.z += acc[6]; o1.w += acc[7];
  *(float4*)o = o0;
  *(float4*)(o + 4) = o1;
}

// ---------------------------------------------------------------------------
// Fallbacks (non-CSR path): plain GEMM + atomic scatter
// ---------------------------------------------------------------------------
__global__ __launch_bounds__(256, 4) void gemm_only(
    const float* __restrict__ x, const unsigned short* __restrict__ Wb,
    const float* __restrict__ bias, float* __restrict__ out,
    unsigned short* __restrict__ xfb, int nN) {
  gemm_tile(blockIdx.x, threadIdx.x, x, Wb, bias, out, xfb, nN);
}

__global__ __launch_bounds__(256) void edge_scatter(
    const unsigned short* __restrict__ xfb, const unsigned short* __restrict__ rfb,
    const int* __restrict__ ei, const int* __restrict__ etype,
    const float* __restrict__ ew, float* __restrict__ out, int nE) {
  const int e = blockIdx.x * 8 + ((int)threadIdx.x >> 5);
  if (e >= nE) return;
  const int lane = threadIdx.x & 31;
  const int s = ei[e];
  const int d = ei[nE + e];
  const int t = etype[e];
  const float w = ew[e];
  const ushort4 a = ((const ushort4*)(xfb + (size_t)s * D))[lane];
  const ushort4 b = ((const ushort4*)(rfb + (size_t)t * D))[lane];
  float* o = out + (size_t)d * D + lane * 4;
  atomicAdd(o + 0, w * (bf2f(a.x) - bf2f(b.x)));
  atomicAdd(o + 1, w * (bf2f(a.y) - bf2f(b.y)));
  atomicAdd(o + 2, w * (bf2f(a.z) - bf2f(b.z)));
  atomicAdd(o + 3, w * (bf2f(a.w) - bf2f(b.w)));
}

// ---------------------------------------------------------------------------
extern "C" void kernel_launch(void* const* d_in, const int* in_sizes, int n_in,
                              void* d_out, int out_size, void* d_ws, size_t ws_size,
                              hipStream_t stream) {
  const float* x      = (const float*)d_in[0];
  const int*   ei     = (const int*)d_in[1];
  const int*   etype  = (const int*)d_in[2];
  const float* rel    = (const float*)d_in[3];
  const float* ew     = (const float*)d_in[4];
  const float* Wself  = (const float*)d_in[5];
  const float* Wfwd   = (const float*)d_in[6];
  const float* Wrel   = (const float*)d_in[7];
  const float* bias   = (const float*)d_in[8];

  const int nN = in_sizes[0] / D;       // 100000
  const int nE = in_sizes[2];           // 625000
  const int nR = in_sizes[3] / D;       // 200

  float* out     = (float*)d_out;
  float* rel_out = (float*)d_out + (size_t)nN * D;

  const int nChunks = (nN + 511) / 512;

  // workspace carve-up (256B-aligned)
  char* w = (char*)d_ws;
  size_t off = 0;
  auto carve = [&](size_t bytes) {
    char* p = w + off;
    off = (off + bytes + 255) & ~(size_t)255;
    return p;
  };
  unsigned short* xfb = (unsigned short*)carve((size_t)nN * D * sizeof(unsigned short));
  unsigned short* rfb = (unsigned short*)carve((size_t)nR * D * sizeof(unsigned short));
  unsigned short* Wb  = (unsigned short*)carve(2 * 8 * 4 * 512 * sizeof(unsigned short));
  char* zbase = w + off;                 // memset region start (offs + flags)
  int*      offs  = (int*)carve((size_t)nChunks * 512 * sizeof(int));
  unsigned* flags = (unsigned*)carve(((size_t)nChunks + 8) * sizeof(unsigned));
  const size_t zbytes = (size_t)((w + off) - zbase);
  uint2* meta = (uint2*)carve((size_t)nE * sizeof(uint2));
  const size_t need = off;

  const int* src = ei;
  const int* dst = ei + nE;
  const int relBlocks  = (nR + 1) / 2;
  const int histBlocks = 256;
  const int gemmBlocks = (nN + 127) / 128;
  const int fillBlocks = 256;

  const bool csr_ok = (need <= ws_size) && (nN < (1 << 20)) && (nR <= 4096);

  if (csr_ok) {
    // 1. zero offs + lookback flags (DMA)
    hipMemsetAsync(zbase, 0, zbytes, stream);
    // 2. Wb prep + rel path + dst histogram
    prep_hist<<<16 + relBlocks + histBlocks, 256, 0, stream>>>(
        Wself, Wfwd, rel, Wrel, dst, Wb, rfb, rel_out, offs,
        nR, nE, relBlocks, histBlocks);
    // 3. exclusive scan (single dispatch, decoupled lookback)
    scan_lookback<<<nChunks, 256, 0, stream>>>(offs, flags, nChunks);
    // 4. node GEMM (MFMA) || fill packed meta
    gemm_fill<<<gemmBlocks + fillBlocks, 256, 0, stream>>>(
        x, Wb, bias, src, dst, etype, ew, out, xfb, offs, meta,
        nN, nE, gemmBlocks, fillBlocks);
    // 5. atomic-free aggregation
    csr_agg<<<(nN + 15) / 16, 256, 0, stream>>>(
        (const uint4*)xfb, (const uint4*)rfb, meta, offs, out, nN);
  } else {
    prep_hist<<<16 + relBlocks, 256, 0, stream>>>(
        Wself, Wfwd, rel, Wrel, dst, Wb, rfb, rel_out, (int*)meta,
        nR, 0, relBlocks, 1);
    gemm_only<<<gemmBlocks, 256, 0, stream>>>(x, Wb, bias, out, xfb, nN);
    edge_scatter<<<(nE + 7) / 8, 256, 0, stream>>>(xfb, rfb, ei, etype, ew, out, nE);
  }
}